// Round 1
// baseline (1000.559 us; speedup 1.0000x reference)
//
#include <hip/hip_runtime.h>
#include <hip/hip_bf16.h>

#define NTOK 8192
#define DIM 1024
#define NEXP 8

typedef float f32x4 __attribute__((ext_vector_type(4)));
typedef short s16x8 __attribute__((ext_vector_type(8)));
typedef unsigned short u16;

__device__ __forceinline__ u16 f2bf(float f) {
    __hip_bfloat16 h = __float2bfloat16(f);
    return *reinterpret_cast<u16*>(&h);
}

#define GLOAD16(gsrc, ldst)                                                     \
    __builtin_amdgcn_global_load_lds(                                           \
        (const __attribute__((address_space(1))) void*)(gsrc),                  \
        (__attribute__((address_space(3))) void*)(ldst), 16, 0, 0)

// ---------------- gates: softmax(z_flat @ Wg^T + bg) ----------------
__global__ __launch_bounds__(256) void gates_kernel(
    const float* __restrict__ zr, const float* __restrict__ zi,
    const float* __restrict__ Wg, const float* __restrict__ bg,
    float* __restrict__ gates)
{
    const int wave = threadIdx.x >> 6, lane = threadIdx.x & 63;
    const int n = blockIdx.x * 4 + wave;

    float v[32];
    const float* zrp = zr + (size_t)n * DIM;
    const float* zip = zi + (size_t)n * DIM;
#pragma unroll
    for (int j = 0; j < 16; ++j) v[j] = zrp[j * 64 + lane];
#pragma unroll
    for (int j = 0; j < 16; ++j) v[16 + j] = zip[j * 64 + lane];

    float s[NEXP];
#pragma unroll
    for (int e = 0; e < NEXP; ++e) {
        const float* wrow = Wg + (size_t)e * (2 * DIM);
        float a = 0.f;
#pragma unroll
        for (int j = 0; j < 32; ++j) a += v[j] * wrow[j * 64 + lane];
#pragma unroll
        for (int m = 32; m; m >>= 1) a += __shfl_xor(a, m);
        s[e] = a + bg[e];
    }
    float mx = s[0];
#pragma unroll
    for (int e = 1; e < NEXP; ++e) mx = fmaxf(mx, s[e]);
    float p[NEXP], sum = 0.f;
#pragma unroll
    for (int e = 0; e < NEXP; ++e) { p[e] = expf(s[e] - mx); sum += p[e]; }
    const float inv = 1.f / sum;
    if (lane == 0) {
#pragma unroll
        for (int e = 0; e < NEXP; ++e) gates[(size_t)n * NEXP + e] = p[e] * inv;
    }
}

// ---------------- weight fp32 -> bf16 conversion ----------------
__global__ __launch_bounds__(256) void cvt_kernel(
    const float* __restrict__ Wr, const float* __restrict__ Wi,
    u16* __restrict__ Wr16, u16* __restrict__ Wi16)
{
    typedef unsigned short u16x4 __attribute__((ext_vector_type(4)));
    const size_t total = (size_t)NEXP * DIM * DIM / 4;
    for (size_t i = (size_t)blockIdx.x * blockDim.x + threadIdx.x; i < total;
         i += (size_t)gridDim.x * blockDim.x) {
        f32x4 a = ((const f32x4*)Wr)[i];
        f32x4 b = ((const f32x4*)Wi)[i];
        u16x4 pa, pb;
#pragma unroll
        for (int j = 0; j < 4; ++j) { pa[j] = f2bf(a[j]); pb[j] = f2bf(b[j]); }
        ((u16x4*)Wr16)[i] = pa;
        ((u16x4*)Wi16)[i] = pb;
    }
}

// ---------------- main fused MoE GEMM ----------------
// grid: (NTOK/128, DIM/128, 2)  block: 256 (4 waves, 2x2 of 64x64)
// C[sel][n][o]: sel=0 -> sum_e g[n,e]*(zr@Wr_e^T - zi@Wi_e^T)
//              sel=1 -> sum_e g[n,e]*(zr@Wi_e^T + zi@Wr_e^T)
// Gate scale (and sign) folded into bf16 conversion of the A tile.
__global__ __launch_bounds__(256) void moe_gemm(
    const float* __restrict__ zr, const float* __restrict__ zi,
    const u16* __restrict__ Wr16, const u16* __restrict__ Wi16,
    const float* __restrict__ gates, float* __restrict__ out)
{
    __shared__ u16 At[128 * 32];
    __shared__ u16 Bt[128 * 32];

    const int bm = blockIdx.x, bn = blockIdx.y, sel = blockIdx.z;
    const int t = threadIdx.x;
    const int lane = t & 63;
    const int wave = t >> 6;
    const int wr = wave >> 1, wc = wave & 1;

    // staging mapping: thread t handles 16B chunk at LDS byte offset t*16 (+4096)
    const int ar = t >> 2;        // row 0..63 (chunk0), +64 (chunk1)
    const int ak = (t & 3) * 8;   // k offset 0,8,16,24
    const int grow0 = bm * 128 + ar;
    const int grow1 = grow0 + 64;

    // fragment read offsets
    const int kg = (lane >> 4) * 8;
    const int rA = wr * 64 + (lane & 15);
    const int rB = wc * 64 + (lane & 15);

    f32x4 acc[4][4];
#pragma unroll
    for (int mi = 0; mi < 4; ++mi)
#pragma unroll
        for (int ni = 0; ni < 4; ++ni)
            acc[mi][ni] = (f32x4){0.f, 0.f, 0.f, 0.f};

#pragma unroll 1
    for (int e = 0; e < NEXP; ++e) {
        const float g0 = gates[(size_t)grow0 * NEXP + e];
        const float g1 = gates[(size_t)grow1 * NEXP + e];
#pragma unroll 1
        for (int half = 0; half < 2; ++half) {
            const float* Asrc = half ? zi : zr;
            const u16* Bsrc = (sel == 0) ? (half ? Wi16 : Wr16)
                                         : (half ? Wr16 : Wi16);
            const float sgn = (sel == 0 && half == 1) ? -1.f : 1.f;
            const float s0 = g0 * sgn, s1 = g1 * sgn;
            const u16* Bbase = Bsrc + ((size_t)(e * DIM + bn * 128 + ar)) * DIM + ak;
            const float* A0 = Asrc + (size_t)grow0 * DIM + ak;
            const float* A1 = Asrc + (size_t)grow1 * DIM + ak;
#pragma unroll 1
            for (int kk = 0; kk < DIM; kk += 32) {
                // A: load 2x8 fp32 to regs
                f32x4 a00 = *(const f32x4*)(A0 + kk);
                f32x4 a01 = *(const f32x4*)(A0 + kk + 4);
                f32x4 a10 = *(const f32x4*)(A1 + kk);
                f32x4 a11 = *(const f32x4*)(A1 + kk + 4);

                __syncthreads();  // prev iteration's ds_reads done

                // B: async global->LDS, 16B per thread per issue
                GLOAD16(Bbase + kk, &Bt[t * 8]);
                GLOAD16(Bbase + kk + (size_t)64 * DIM, &Bt[2048 + t * 8]);

                // A: convert+scale to bf16, write to LDS
                s16x8 w0, w1;
                w0[0] = (short)f2bf(a00[0] * s0);
                w0[1] = (short)f2bf(a00[1] * s0);
                w0[2] = (short)f2bf(a00[2] * s0);
                w0[3] = (short)f2bf(a00[3] * s0);
                w0[4] = (short)f2bf(a01[0] * s0);
                w0[5] = (short)f2bf(a01[1] * s0);
                w0[6] = (short)f2bf(a01[2] * s0);
                w0[7] = (short)f2bf(a01[3] * s0);
                w1[0] = (short)f2bf(a10[0] * s1);
                w1[1] = (short)f2bf(a10[1] * s1);
                w1[2] = (short)f2bf(a10[2] * s1);
                w1[3] = (short)f2bf(a10[3] * s1);
                w1[4] = (short)f2bf(a11[0] * s1);
                w1[5] = (short)f2bf(a11[1] * s1);
                w1[6] = (short)f2bf(a11[2] * s1);
                w1[7] = (short)f2bf(a11[3] * s1);
                *(s16x8*)(&At[t * 8]) = w0;
                *(s16x8*)(&At[2048 + t * 8]) = w1;

                __syncthreads();  // LDS tiles ready (vmcnt+lgkmcnt drained)

                // fragments + MFMA
                s16x8 af[4], bfr[4];
#pragma unroll
                for (int mi = 0; mi < 4; ++mi)
                    af[mi] = *(const s16x8*)&At[(rA + mi * 16) * 32 + kg];
#pragma unroll
                for (int ni = 0; ni < 4; ++ni)
                    bfr[ni] = *(const s16x8*)&Bt[(rB + ni * 16) * 32 + kg];
#pragma unroll
                for (int mi = 0; mi < 4; ++mi)
#pragma unroll
                    for (int ni = 0; ni < 4; ++ni)
                        acc[mi][ni] = __builtin_amdgcn_mfma_f32_16x16x32_bf16(
                            af[mi], bfr[ni], acc[mi][ni], 0, 0, 0);
            }
        }
    }

    // epilogue: C[row][col], col=lane&15, row=(lane>>4)*4+j  (m89 layout)
    float* op = out + (size_t)sel * NTOK * DIM;
    const int col = bn * 128 + wc * 64 + (lane & 15);
    const int row0 = bm * 128 + wr * 64 + ((lane >> 4) << 2);
#pragma unroll
    for (int mi = 0; mi < 4; ++mi)
#pragma unroll
        for (int ni = 0; ni < 4; ++ni)
#pragma unroll
            for (int j = 0; j < 4; ++j)
                op[(size_t)(row0 + mi * 16 + j) * DIM + col + ni * 16] =
                    acc[mi][ni][j];
}

extern "C" void kernel_launch(void* const* d_in, const int* in_sizes, int n_in,
                              void* d_out, int out_size, void* d_ws, size_t ws_size,
                              hipStream_t stream) {
    const float* zr = (const float*)d_in[0];
    const float* zi = (const float*)d_in[1];
    const float* Wg = (const float*)d_in[2];
    const float* bg = (const float*)d_in[3];
    const float* Wr = (const float*)d_in[4];
    const float* Wi = (const float*)d_in[5];
    float* out = (float*)d_out;

    u16* Wr16 = (u16*)d_ws;
    u16* Wi16 = Wr16 + (size_t)NEXP * DIM * DIM;
    float* gates = (float*)(Wi16 + (size_t)NEXP * DIM * DIM);

    cvt_kernel<<<2048, 256, 0, stream>>>(Wr, Wi, Wr16, Wi16);
    gates_kernel<<<NTOK / 4, 256, 0, stream>>>(zr, zi, Wg, bg, gates);

    dim3 grid(NTOK / 128, DIM / 128, 2);
    moe_gemm<<<grid, 256, 0, stream>>>(zr, zi, Wr16, Wi16, gates, out);
}

// Round 2
// 718.545 us; speedup vs baseline: 1.3925x; 1.3925x over previous
//
#include <hip/hip_runtime.h>
#include <hip/hip_bf16.h>

#define NTOK 8192
#define DIM 1024
#define NEXP 8

typedef float f32x4 __attribute__((ext_vector_type(4)));
typedef short s16x8 __attribute__((ext_vector_type(8)));
typedef unsigned short u16;
typedef unsigned short u16x4 __attribute__((ext_vector_type(4)));

__device__ __forceinline__ u16 f2bf(float f) {
    __hip_bfloat16 h = __float2bfloat16(f);
    return *reinterpret_cast<u16*>(&h);
}

#define GLOAD16(gsrc, ldst)                                                     \
    __builtin_amdgcn_global_load_lds(                                           \
        (const __attribute__((address_space(1))) void*)(gsrc),                  \
        (__attribute__((address_space(3))) void*)(ldst), 16, 0, 0)

// ---------------- gates: softmax(z_flat @ Wg^T + bg) ----------------
__global__ __launch_bounds__(256) void gates_kernel(
    const float* __restrict__ zr, const float* __restrict__ zi,
    const float* __restrict__ Wg, const float* __restrict__ bg,
    float* __restrict__ gates)
{
    const int wave = threadIdx.x >> 6, lane = threadIdx.x & 63;
    const int n = blockIdx.x * 4 + wave;

    float v[32];
    const float* zrp = zr + (size_t)n * DIM;
    const float* zip = zi + (size_t)n * DIM;
#pragma unroll
    for (int j = 0; j < 16; ++j) v[j] = zrp[j * 64 + lane];
#pragma unroll
    for (int j = 0; j < 16; ++j) v[16 + j] = zip[j * 64 + lane];

    float s[NEXP];
#pragma unroll
    for (int e = 0; e < NEXP; ++e) {
        const float* wrow = Wg + (size_t)e * (2 * DIM);
        float a = 0.f;
#pragma unroll
        for (int j = 0; j < 32; ++j) a += v[j] * wrow[j * 64 + lane];
#pragma unroll
        for (int m = 32; m; m >>= 1) a += __shfl_xor(a, m);
        s[e] = a + bg[e];
    }
    float mx = s[0];
#pragma unroll
    for (int e = 1; e < NEXP; ++e) mx = fmaxf(mx, s[e]);
    float p[NEXP], sum = 0.f;
#pragma unroll
    for (int e = 0; e < NEXP; ++e) { p[e] = expf(s[e] - mx); sum += p[e]; }
    const float inv = 1.f / sum;
    if (lane == 0) {
#pragma unroll
        for (int e = 0; e < NEXP; ++e) gates[(size_t)n * NEXP + e] = p[e] * inv;
    }
}

// ---------------- fp32 -> bf16 conversion (z and W; equal element counts) ---
__global__ __launch_bounds__(256) void cvt4_kernel(
    const float* __restrict__ zr, const float* __restrict__ zi,
    const float* __restrict__ Wr, const float* __restrict__ Wi,
    u16* __restrict__ zr16, u16* __restrict__ zi16,
    u16* __restrict__ Wr16, u16* __restrict__ Wi16)
{
    const size_t total = (size_t)NEXP * DIM * DIM / 4;  // == NTOK*DIM/4
    for (size_t i = (size_t)blockIdx.x * 256 + threadIdx.x; i < total;
         i += (size_t)gridDim.x * 256) {
        f32x4 a = ((const f32x4*)zr)[i];
        f32x4 b = ((const f32x4*)zi)[i];
        f32x4 c = ((const f32x4*)Wr)[i];
        f32x4 d = ((const f32x4*)Wi)[i];
        u16x4 pa, pb, pc, pd;
#pragma unroll
        for (int j = 0; j < 4; ++j) {
            pa[j] = f2bf(a[j]); pb[j] = f2bf(b[j]);
            pc[j] = f2bf(c[j]); pd[j] = f2bf(d[j]);
        }
        ((u16x4*)zr16)[i] = pa;
        ((u16x4*)zi16)[i] = pb;
        ((u16x4*)Wr16)[i] = pc;
        ((u16x4*)Wi16)[i] = pd;
    }
}

// ---------------- main MoE GEMM, epilogue-gated (m97 structure) ----------------
// grid: (NTOK/128, DIM/128, 2)  block: 256 (4 waves, 2x2 of 64x64)
// Per expert+half: unscaled bf16 GEMM into acc; then tot += sgn*g[row,e]*acc.
// LDS XOR swizzle: elem ^= ((row>>1)&3)<<3, applied via pre-swizzled global src.
__global__ __launch_bounds__(256, 2) void moe_gemm2(
    const u16* __restrict__ zr16, const u16* __restrict__ zi16,
    const u16* __restrict__ Wr16, const u16* __restrict__ Wi16,
    const float* __restrict__ gates, float* __restrict__ out)
{
    __shared__ u16 At[128 * 32];
    __shared__ u16 Bt[128 * 32];

    const int bm = blockIdx.x, bn = blockIdx.y, sel = blockIdx.z;
    const int t = threadIdx.x;
    const int lane = t & 63;
    const int wave = t >> 6;
    const int wr = wave >> 1, wc = wave & 1;

    // staging: thread t fills 16B at LDS byte t*16 (chunk0: rows 0..63) and
    // +4096 (chunk1: rows 64..127). Global k pre-swizzled so that the
    // swizzled read below sees linear data.
    const int srow = t >> 2;                              // row within tile
    const int skel = (((t & 3) ^ ((t >> 3) & 3)) << 3);   // swizzled k elem
    const size_t aoff0 = (size_t)(bm * 128 + srow) * DIM + skel;
    const size_t aoff1 = aoff0 + (size_t)64 * DIM;
    const size_t boffB = (size_t)(bn * 128 + srow) * DIM + skel;

    // fragment read offsets (u16 elements), XOR-swizzled
    const int kg = (lane >> 4) * 8;
    const int rA = wr * 64 + (lane & 15);
    const int rB = wc * 64 + (lane & 15);
    const int swz = ((lane >> 1) & 3) << 3;
    const int eoffA = (rA * 32 + kg) ^ swz;
    const int eoffB = (rB * 32 + kg) ^ swz;

    const int row0 = bm * 128 + wr * 64 + ((lane >> 4) << 2);

    f32x4 tot[4][4];
#pragma unroll
    for (int mi = 0; mi < 4; ++mi)
#pragma unroll
        for (int ni = 0; ni < 4; ++ni)
            tot[mi][ni] = (f32x4){0.f, 0.f, 0.f, 0.f};

#pragma unroll 1
    for (int e = 0; e < NEXP; ++e) {
#pragma unroll 1
        for (int half = 0; half < 2; ++half) {
            const u16* Ab = half ? zi16 : zr16;
            const u16* Bb = (sel == 0) ? (half ? Wi16 : Wr16)
                                       : (half ? Wr16 : Wi16);
            const u16* A0 = Ab + aoff0;
            const u16* A1 = Ab + aoff1;
            const u16* B0 = Bb + (size_t)e * DIM * DIM + boffB;
            const u16* B1 = B0 + (size_t)64 * DIM;

            f32x4 acc[4][4];
#pragma unroll
            for (int mi = 0; mi < 4; ++mi)
#pragma unroll
                for (int ni = 0; ni < 4; ++ni)
                    acc[mi][ni] = (f32x4){0.f, 0.f, 0.f, 0.f};

#pragma unroll 1
            for (int kk = 0; kk < DIM; kk += 32) {
                __syncthreads();  // prev ds_reads done before overwrite
                GLOAD16(A0 + kk, &At[t * 8]);
                GLOAD16(A1 + kk, &At[2048 + t * 8]);
                GLOAD16(B0 + kk, &Bt[t * 8]);
                GLOAD16(B1 + kk, &Bt[2048 + t * 8]);
                __syncthreads();  // glds drained (vmcnt0 before barrier)

                s16x8 af[4], bfr[4];
#pragma unroll
                for (int mi = 0; mi < 4; ++mi)
                    af[mi] = *(const s16x8*)&At[eoffA + mi * 512];
#pragma unroll
                for (int ni = 0; ni < 4; ++ni)
                    bfr[ni] = *(const s16x8*)&Bt[eoffB + ni * 512];
#pragma unroll
                for (int mi = 0; mi < 4; ++mi)
#pragma unroll
                    for (int ni = 0; ni < 4; ++ni)
                        acc[mi][ni] = __builtin_amdgcn_mfma_f32_16x16x32_bf16(
                            af[mi], bfr[ni], acc[mi][ni], 0, 0, 0);
            }

            // epilogue: tot += sgn * g[row,e] * acc
            const float sgn = (sel == 0 && half == 1) ? -1.f : 1.f;
#pragma unroll
            for (int mi = 0; mi < 4; ++mi) {
                const size_t rbase = (size_t)(row0 + mi * 16) * NEXP + e;
                float s0 = sgn * gates[rbase];
                float s1 = sgn * gates[rbase + NEXP];
                float s2 = sgn * gates[rbase + 2 * NEXP];
                float s3 = sgn * gates[rbase + 3 * NEXP];
#pragma unroll
                for (int ni = 0; ni < 4; ++ni) {
                    tot[mi][ni][0] += s0 * acc[mi][ni][0];
                    tot[mi][ni][1] += s1 * acc[mi][ni][1];
                    tot[mi][ni][2] += s2 * acc[mi][ni][2];
                    tot[mi][ni][3] += s3 * acc[mi][ni][3];
                }
            }
        }
    }

    // C write: col=lane&15 (+ni*16), row=(lane>>4)*4+j (+mi*16)  (m89 layout)
    float* op = out + (size_t)sel * NTOK * DIM;
    const int col = bn * 128 + wc * 64 + (lane & 15);
#pragma unroll
    for (int mi = 0; mi < 4; ++mi)
#pragma unroll
        for (int ni = 0; ni < 4; ++ni)
#pragma unroll
            for (int j = 0; j < 4; ++j)
                op[(size_t)(row0 + mi * 16 + j) * DIM + col + ni * 16] =
                    tot[mi][ni][j];
}

// ================= fallback path (round-0 kernel, ws too small) =================
__global__ __launch_bounds__(256) void cvt_kernel(
    const float* __restrict__ Wr, const float* __restrict__ Wi,
    u16* __restrict__ Wr16, u16* __restrict__ Wi16)
{
    const size_t total = (size_t)NEXP * DIM * DIM / 4;
    for (size_t i = (size_t)blockIdx.x * blockDim.x + threadIdx.x; i < total;
         i += (size_t)gridDim.x * blockDim.x) {
        f32x4 a = ((const f32x4*)Wr)[i];
        f32x4 b = ((const f32x4*)Wi)[i];
        u16x4 pa, pb;
#pragma unroll
        for (int j = 0; j < 4; ++j) { pa[j] = f2bf(a[j]); pb[j] = f2bf(b[j]); }
        ((u16x4*)Wr16)[i] = pa;
        ((u16x4*)Wi16)[i] = pb;
    }
}

__global__ __launch_bounds__(256) void moe_gemm(
    const float* __restrict__ zr, const float* __restrict__ zi,
    const u16* __restrict__ Wr16, const u16* __restrict__ Wi16,
    const float* __restrict__ gates, float* __restrict__ out)
{
    __shared__ u16 At[128 * 32];
    __shared__ u16 Bt[128 * 32];

    const int bm = blockIdx.x, bn = blockIdx.y, sel = blockIdx.z;
    const int t = threadIdx.x;
    const int lane = t & 63;
    const int wave = t >> 6;
    const int wr = wave >> 1, wc = wave & 1;
    const int ar = t >> 2;
    const int ak = (t & 3) * 8;
    const int grow0 = bm * 128 + ar;
    const int grow1 = grow0 + 64;
    const int kg = (lane >> 4) * 8;
    const int rA = wr * 64 + (lane & 15);
    const int rB = wc * 64 + (lane & 15);

    f32x4 acc[4][4];
#pragma unroll
    for (int mi = 0; mi < 4; ++mi)
#pragma unroll
        for (int ni = 0; ni < 4; ++ni)
            acc[mi][ni] = (f32x4){0.f, 0.f, 0.f, 0.f};

#pragma unroll 1
    for (int e = 0; e < NEXP; ++e) {
        const float g0 = gates[(size_t)grow0 * NEXP + e];
        const float g1 = gates[(size_t)grow1 * NEXP + e];
#pragma unroll 1
        for (int half = 0; half < 2; ++half) {
            const float* Asrc = half ? zi : zr;
            const u16* Bsrc = (sel == 0) ? (half ? Wi16 : Wr16)
                                         : (half ? Wr16 : Wi16);
            const float sgn = (sel == 0 && half == 1) ? -1.f : 1.f;
            const float s0 = g0 * sgn, s1 = g1 * sgn;
            const u16* Bbase = Bsrc + ((size_t)(e * DIM + bn * 128 + ar)) * DIM + ak;
            const float* A0 = Asrc + (size_t)grow0 * DIM + ak;
            const float* A1 = Asrc + (size_t)grow1 * DIM + ak;
#pragma unroll 1
            for (int kk = 0; kk < DIM; kk += 32) {
                f32x4 a00 = *(const f32x4*)(A0 + kk);
                f32x4 a01 = *(const f32x4*)(A0 + kk + 4);
                f32x4 a10 = *(const f32x4*)(A1 + kk);
                f32x4 a11 = *(const f32x4*)(A1 + kk + 4);
                __syncthreads();
                GLOAD16(Bbase + kk, &Bt[t * 8]);
                GLOAD16(Bbase + kk + (size_t)64 * DIM, &Bt[2048 + t * 8]);
                s16x8 w0, w1;
                w0[0] = (short)f2bf(a00[0] * s0);
                w0[1] = (short)f2bf(a00[1] * s0);
                w0[2] = (short)f2bf(a00[2] * s0);
                w0[3] = (short)f2bf(a00[3] * s0);
                w0[4] = (short)f2bf(a01[0] * s0);
                w0[5] = (short)f2bf(a01[1] * s0);
                w0[6] = (short)f2bf(a01[2] * s0);
                w0[7] = (short)f2bf(a01[3] * s0);
                w1[0] = (short)f2bf(a10[0] * s1);
                w1[1] = (short)f2bf(a10[1] * s1);
                w1[2] = (short)f2bf(a10[2] * s1);
                w1[3] = (short)f2bf(a10[3] * s1);
                w1[4] = (short)f2bf(a11[0] * s1);
                w1[5] = (short)f2bf(a11[1] * s1);
                w1[6] = (short)f2bf(a11[2] * s1);
                w1[7] = (short)f2bf(a11[3] * s1);
                *(s16x8*)(&At[t * 8]) = w0;
                *(s16x8*)(&At[2048 + t * 8]) = w1;
                __syncthreads();
                s16x8 af[4], bfr[4];
#pragma unroll
                for (int mi = 0; mi < 4; ++mi)
                    af[mi] = *(const s16x8*)&At[(rA + mi * 16) * 32 + kg];
#pragma unroll
                for (int ni = 0; ni < 4; ++ni)
                    bfr[ni] = *(const s16x8*)&Bt[(rB + ni * 16) * 32 + kg];
#pragma unroll
                for (int mi = 0; mi < 4; ++mi)
#pragma unroll
                    for (int ni = 0; ni < 4; ++ni)
                        acc[mi][ni] = __builtin_amdgcn_mfma_f32_16x16x32_bf16(
                            af[mi], bfr[ni], acc[mi][ni], 0, 0, 0);
            }
        }
    }

    float* op = out + (size_t)sel * NTOK * DIM;
    const int col = bn * 128 + wc * 64 + (lane & 15);
    const int row0 = bm * 128 + wr * 64 + ((lane >> 4) << 2);
#pragma unroll
    for (int mi = 0; mi < 4; ++mi)
#pragma unroll
        for (int ni = 0; ni < 4; ++ni)
#pragma unroll
            for (int j = 0; j < 4; ++j)
                op[(size_t)(row0 + mi * 16 + j) * DIM + col + ni * 16] =
                    acc[mi][ni][j];
}

extern "C" void kernel_launch(void* const* d_in, const int* in_sizes, int n_in,
                              void* d_out, int out_size, void* d_ws, size_t ws_size,
                              hipStream_t stream) {
    const float* zr = (const float*)d_in[0];
    const float* zi = (const float*)d_in[1];
    const float* Wg = (const float*)d_in[2];
    const float* bg = (const float*)d_in[3];
    const float* Wr = (const float*)d_in[4];
    const float* Wi = (const float*)d_in[5];
    float* out = (float*)d_out;

    const size_t NELEM = (size_t)NEXP * DIM * DIM;  // == NTOK*DIM
    const size_t need_big = 4 * NELEM * sizeof(u16) + (size_t)NTOK * NEXP * sizeof(float);

    if (ws_size >= need_big) {
        u16* zr16 = (u16*)d_ws;
        u16* zi16 = zr16 + NELEM;
        u16* Wr16 = zi16 + NELEM;
        u16* Wi16 = Wr16 + NELEM;
        float* gates = (float*)(Wi16 + NELEM);

        cvt4_kernel<<<2048, 256, 0, stream>>>(zr, zi, Wr, Wi, zr16, zi16, Wr16, Wi16);
        gates_kernel<<<NTOK / 4, 256, 0, stream>>>(zr, zi, Wg, bg, gates);

        dim3 grid(NTOK / 128, DIM / 128, 2);
        moe_gemm2<<<grid, 256, 0, stream>>>(zr16, zi16, Wr16, Wi16, gates, out);
    } else {
        u16* Wr16 = (u16*)d_ws;
        u16* Wi16 = Wr16 + NELEM;
        float* gates = (float*)(Wi16 + NELEM);

        cvt_kernel<<<2048, 256, 0, stream>>>(Wr, Wi, Wr16, Wi16);
        gates_kernel<<<NTOK / 4, 256, 0, stream>>>(zr, zi, Wg, bg, gates);

        dim3 grid(NTOK / 128, DIM / 128, 2);
        moe_gemm<<<grid, 256, 0, stream>>>(zr, zi, Wr16, Wi16, gates, out);
    }
}

// Round 3
// 685.578 us; speedup vs baseline: 1.4594x; 1.0481x over previous
//
#include <hip/hip_runtime.h>
#include <hip/hip_bf16.h>

#define NTOK 8192
#define DIM 1024
#define NEXP 8
#define NT 256   // virtual K tiles: 16 segments (expert x half) x 16 tiles of BK=64
#define BK 64

typedef float f32x4 __attribute__((ext_vector_type(4)));
typedef short s16x8 __attribute__((ext_vector_type(8)));
typedef unsigned short u16;
typedef unsigned short u16x4 __attribute__((ext_vector_type(4)));

__device__ __forceinline__ u16 f2bf(float f) {
    __hip_bfloat16 h = __float2bfloat16(f);
    return *reinterpret_cast<u16*>(&h);
}

#define GLOAD16(gsrc, ldst)                                                     \
    __builtin_amdgcn_global_load_lds(                                           \
        (const __attribute__((address_space(1))) void*)(gsrc),                  \
        (__attribute__((address_space(3))) void*)(ldst), 16, 0, 0)

#define MFMA16(a, b, c) __builtin_amdgcn_mfma_f32_16x16x32_bf16((a), (b), (c), 0, 0, 0)

// ---------------- gates: softmax(z_flat @ Wg^T + bg) ----------------
__global__ __launch_bounds__(256) void gates_kernel(
    const float* __restrict__ zr, const float* __restrict__ zi,
    const float* __restrict__ Wg, const float* __restrict__ bg,
    float* __restrict__ gates)
{
    const int wave = threadIdx.x >> 6, lane = threadIdx.x & 63;
    const int n = blockIdx.x * 4 + wave;

    float v[32];
    const float* zrp = zr + (size_t)n * DIM;
    const float* zip = zi + (size_t)n * DIM;
#pragma unroll
    for (int j = 0; j < 16; ++j) v[j] = zrp[j * 64 + lane];
#pragma unroll
    for (int j = 0; j < 16; ++j) v[16 + j] = zip[j * 64 + lane];

    float s[NEXP];
#pragma unroll
    for (int e = 0; e < NEXP; ++e) {
        const float* wrow = Wg + (size_t)e * (2 * DIM);
        float a = 0.f;
#pragma unroll
        for (int j = 0; j < 32; ++j) a += v[j] * wrow[j * 64 + lane];
#pragma unroll
        for (int m = 32; m; m >>= 1) a += __shfl_xor(a, m);
        s[e] = a + bg[e];
    }
    float mx = s[0];
#pragma unroll
    for (int e = 1; e < NEXP; ++e) mx = fmaxf(mx, s[e]);
    float p[NEXP], sum = 0.f;
#pragma unroll
    for (int e = 0; e < NEXP; ++e) { p[e] = expf(s[e] - mx); sum += p[e]; }
    const float inv = 1.f / sum;
    if (lane == 0) {
#pragma unroll
        for (int e = 0; e < NEXP; ++e) gates[(size_t)n * NEXP + e] = p[e] * inv;
    }
}

// ---------------- weight fp32 -> bf16 ----------------
__global__ __launch_bounds__(256) void cvt2_kernel(
    const float* __restrict__ Wr, const float* __restrict__ Wi,
    u16* __restrict__ Wr16, u16* __restrict__ Wi16)
{
    const size_t total = (size_t)NEXP * DIM * DIM / 4;
    for (size_t i = (size_t)blockIdx.x * 256 + threadIdx.x; i < total;
         i += (size_t)gridDim.x * 256) {
        f32x4 a = ((const f32x4*)Wr)[i];
        f32x4 b = ((const f32x4*)Wi)[i];
        u16x4 pa, pb;
#pragma unroll
        for (int j = 0; j < 4; ++j) { pa[j] = f2bf(a[j]); pb[j] = f2bf(b[j]); }
        ((u16x4*)Wr16)[i] = pa;
        ((u16x4*)Wi16)[i] = pb;
    }
}

// ---------------- main MoE GEMM: 256x256 tile, 4-phase/K-tile pipeline --------
// grid (NTOK/256, DIM/256, 2), 512 threads = 8 waves (2M x 4N), per-wave 128x64.
// Virtual K = 16 segments x 1024; gate*sign folded into A-staging conversion.
// LDS: 2 bufs x (A 256x64 + B 256x64) bf16 = 128 KiB (dynamic).
// Swizzle: 16B-chunk c ^= (row&7), inverse applied on global source (rule #21).
__global__ __launch_bounds__(512, 2) void moe_gemm3(
    const float* __restrict__ zr, const float* __restrict__ zi,
    const u16* __restrict__ Wr16, const u16* __restrict__ Wi16,
    const float* __restrict__ gates, float* __restrict__ out)
{
    extern __shared__ u16 lds[];  // [2][32768]: per buf: A[0..16383], B[16384..32767]

    const int bm = blockIdx.x, bn = blockIdx.y, sel = blockIdx.z;
    const int tid = threadIdx.x;
    const int lane = tid & 63;
    const int wid = tid >> 6;
    const int wr = wid >> 2;   // 0..1
    const int wc = wid & 3;    // 0..3

    // ---- staging addressing ----
    const int srow = tid >> 3;                     // 0..63
    const int schunk = (tid & 7) ^ (srow & 7);     // inverse-swizzled global chunk
    int arow[4], gidx[4], brow[4];
#pragma unroll
    for (int j = 0; j < 4; ++j) {
        const int gr = bm * 256 + srow + j * 64;
        arow[j] = gr * DIM + schunk * 8;
        gidx[j] = gr * NEXP;
        brow[j] = (bn * 256 + srow + j * 64) * DIM + schunk * 8;
    }

    // ---- fragment read addressing ----
    const int cg = lane >> 4;            // k-group 0..3
    const int l7 = lane & 7;
    const int ach0 = (cg ^ l7) * 8;      // ks=0 chunk elem offset
    const int ach1 = ((4 + cg) ^ l7) * 8;
    const int arbase = (wr * 128 + (lane & 15)) * BK;
    const int brbase = 16384 + (wc * 64 + (lane & 15)) * BK;

    f32x4 acc[8][4];
#pragma unroll
    for (int m = 0; m < 8; ++m)
#pragma unroll
        for (int n = 0; n < 4; ++n) acc[m][n] = (f32x4){0.f, 0.f, 0.f, 0.f};

    // ---- segment 0 state ----
    const float* Asrc = sel ? zi : zr;   // (half=0)^sel
    const u16* Bseg = Wr16;              // e=0, half=0
    float sg[4];
#pragma unroll
    for (int j = 0; j < 4; ++j) sg[j] = gates[gidx[j]];

    // ---- prologue: stage tile 0 into buf 0 ----
    {
        f32x4 ga[4][2];
#pragma unroll
        for (int j = 0; j < 4; ++j) {
            const float* p = Asrc + arow[j];
            ga[j][0] = *(const f32x4*)p;
            ga[j][1] = *(const f32x4*)(p + 4);
        }
#pragma unroll
        for (int i = 0; i < 4; ++i)
            GLOAD16(Bseg + brow[i], &lds[16384 + (i * 512 + tid) * 8]);
#pragma unroll
        for (int j = 0; j < 4; ++j) {
            s16x8 w;
#pragma unroll
            for (int q = 0; q < 4; ++q) {
                w[q] = (short)f2bf(ga[j][0][q] * sg[j]);
                w[4 + q] = (short)f2bf(ga[j][1][q] * sg[j]);
            }
            *(s16x8*)&lds[(tid + j * 512) * 8] = w;
        }
        asm volatile("s_waitcnt vmcnt(0)" ::: "memory");
        __syncthreads();
    }

    int buf = 0;
#pragma unroll 1
    for (int t = 0; t < NT; ++t) {
        const int tn = t + 1;
        if ((tn & 15) == 0) {  // segment boundary: state for tiles tn..tn+15
            const int seg = tn >> 4;
            const int e = (seg >> 1) & 7;  // seg 16 (dead staged tile): wraps, unused
            const int half = seg & 1;
            Asrc = (half ^ sel) ? zi : zr;
            Bseg = (half ? Wi16 : Wr16) + (size_t)e * DIM * DIM;
            const float sgn = (sel == 0 && half == 1) ? -1.f : 1.f;
#pragma unroll
            for (int j = 0; j < 4; ++j) sg[j] = sgn * gates[gidx[j] + e];
        }
        const int kb = (tn & 15) << 6;       // staging k base (elems)
        const int ab = (buf << 15) + arbase; // read bases for this tile
        const int bb = (buf << 15) + brbase;
        const int sb = (buf ^ 1) << 15;      // staging dest base

        // ==== ph0: issue A loads (t+1); vmcnt gate; dsr B[ks0]+A[0..3,ks0]; MFMA
        f32x4 ga[4][2];
#pragma unroll
        for (int j = 0; j < 4; ++j) {
            const float* p = Asrc + arow[j] + kb;
            ga[j][0] = *(const f32x4*)p;
            ga[j][1] = *(const f32x4*)(p + 4);
        }
        // drain the 4 B-gloads staged for THIS tile; keep the 8 A-loads in flight
        asm volatile("s_waitcnt vmcnt(8)" ::: "memory");
        s16x8 bf0[4], afr[4];
#pragma unroll
        for (int n = 0; n < 4; ++n) bf0[n] = *(const s16x8*)&lds[bb + n * 1024 + ach0];
#pragma unroll
        for (int m = 0; m < 4; ++m) afr[m] = *(const s16x8*)&lds[ab + m * 1024 + ach0];
        __builtin_amdgcn_s_barrier();
        __builtin_amdgcn_s_setprio(1);
#pragma unroll
        for (int m = 0; m < 4; ++m)
#pragma unroll
            for (int n = 0; n < 4; ++n) acc[m][n] = MFMA16(afr[m], bf0[n], acc[m][n]);
        __builtin_amdgcn_s_setprio(0);
        __builtin_amdgcn_s_barrier();

        // ==== ph1: dsr A[4..7,ks0]; issue b0,b1 (t+1); MFMA
#pragma unroll
        for (int m = 0; m < 4; ++m) afr[m] = *(const s16x8*)&lds[ab + (m + 4) * 1024 + ach0];
        GLOAD16(Bseg + brow[0] + kb, &lds[sb + 16384 + (0 * 512 + tid) * 8]);
        GLOAD16(Bseg + brow[1] + kb, &lds[sb + 16384 + (1 * 512 + tid) * 8]);
        __builtin_amdgcn_s_barrier();
        __builtin_amdgcn_s_setprio(1);
#pragma unroll
        for (int m = 0; m < 4; ++m)
#pragma unroll
            for (int n = 0; n < 4; ++n) acc[m + 4][n] = MFMA16(afr[m], bf0[n], acc[m + 4][n]);
        __builtin_amdgcn_s_setprio(0);
        __builtin_amdgcn_s_barrier();

        // ==== ph2: dsr B[ks1]+A[0..3,ks1]; issue b2,b3; cvt+write A j=0,1; MFMA
        s16x8 bf1[4];
#pragma unroll
        for (int n = 0; n < 4; ++n) bf1[n] = *(const s16x8*)&lds[bb + n * 1024 + ach1];
#pragma unroll
        for (int m = 0; m < 4; ++m) afr[m] = *(const s16x8*)&lds[ab + m * 1024 + ach1];
        GLOAD16(Bseg + brow[2] + kb, &lds[sb + 16384 + (2 * 512 + tid) * 8]);
        GLOAD16(Bseg + brow[3] + kb, &lds[sb + 16384 + (3 * 512 + tid) * 8]);
#pragma unroll
        for (int j = 0; j < 2; ++j) {
            s16x8 w;
#pragma unroll
            for (int q = 0; q < 4; ++q) {
                w[q] = (short)f2bf(ga[j][0][q] * sg[j]);
                w[4 + q] = (short)f2bf(ga[j][1][q] * sg[j]);
            }
            *(s16x8*)&lds[sb + (tid + j * 512) * 8] = w;
        }
        __builtin_amdgcn_s_barrier();
        __builtin_amdgcn_s_setprio(1);
#pragma unroll
        for (int m = 0; m < 4; ++m)
#pragma unroll
            for (int n = 0; n < 4; ++n) acc[m][n] = MFMA16(afr[m], bf1[n], acc[m][n]);
        __builtin_amdgcn_s_setprio(0);
        __builtin_amdgcn_s_barrier();

        // ==== ph3: dsr A[4..7,ks1]; cvt+write A j=2,3; MFMA; lgkm drain
#pragma unroll
        for (int m = 0; m < 4; ++m) afr[m] = *(const s16x8*)&lds[ab + (m + 4) * 1024 + ach1];
#pragma unroll
        for (int j = 2; j < 4; ++j) {
            s16x8 w;
#pragma unroll
            for (int q = 0; q < 4; ++q) {
                w[q] = (short)f2bf(ga[j][0][q] * sg[j]);
                w[4 + q] = (short)f2bf(ga[j][1][q] * sg[j]);
            }
            *(s16x8*)&lds[sb + (tid + j * 512) * 8] = w;
        }
        __builtin_amdgcn_s_barrier();
        __builtin_amdgcn_s_setprio(1);
#pragma unroll
        for (int m = 0; m < 4; ++m)
#pragma unroll
            for (int n = 0; n < 4; ++n) acc[m + 4][n] = MFMA16(afr[m], bf1[n], acc[m + 4][n]);
        __builtin_amdgcn_s_setprio(0);
        // make this wave's ds_writes visible before anyone reads them next tile
        asm volatile("s_waitcnt lgkmcnt(0)" ::: "memory");
        __builtin_amdgcn_s_barrier();

        buf ^= 1;
    }
    asm volatile("s_waitcnt vmcnt(0)" ::: "memory");  // drain dead staged tile
    __builtin_amdgcn_s_barrier();

    // ---- epilogue: C[row][col], col=lane&15, row=(lane>>4)*4+j (m89 layout) ----
    float* op = out + (size_t)sel * NTOK * DIM;
    const int col0 = bn * 256 + wc * 64 + (lane & 15);
    const int row0 = bm * 256 + wr * 128 + ((lane >> 4) << 2);
#pragma unroll
    for (int m = 0; m < 8; ++m)
#pragma unroll
        for (int n = 0; n < 4; ++n)
#pragma unroll
            for (int j = 0; j < 4; ++j)
                op[(size_t)(row0 + m * 16 + j) * DIM + col0 + n * 16] = acc[m][n][j];
}

extern "C" void kernel_launch(void* const* d_in, const int* in_sizes, int n_in,
                              void* d_out, int out_size, void* d_ws, size_t ws_size,
                              hipStream_t stream) {
    const float* zr = (const float*)d_in[0];
    const float* zi = (const float*)d_in[1];
    const float* Wg = (const float*)d_in[2];
    const float* bg = (const float*)d_in[3];
    const float* Wr = (const float*)d_in[4];
    const float* Wi = (const float*)d_in[5];
    float* out = (float*)d_out;

    const size_t NELEM = (size_t)NEXP * DIM * DIM;
    u16* Wr16 = (u16*)d_ws;
    u16* Wi16 = Wr16 + NELEM;
    float* gates = (float*)(Wi16 + NELEM);  // NTOK*NEXP + 64 pad (dead-tile reads)

    cvt2_kernel<<<2048, 256, 0, stream>>>(Wr, Wi, Wr16, Wi16);
    gates_kernel<<<NTOK / 4, 256, 0, stream>>>(zr, zi, Wg, bg, gates);

    hipFuncSetAttribute((const void*)moe_gemm3,
                        hipFuncAttributeMaxDynamicSharedMemorySize, 131072);
    dim3 grid(NTOK / 256, DIM / 256, 2);
    moe_gemm3<<<grid, 512, 131072, stream>>>(zr, zi, Wr16, Wi16, gates, out);
}